// Round 1
// baseline (2044.676 us; speedup 1.0000x reference)
//
#include <hip/hip_runtime.h>
#include <math.h>

#define N_NODES 50000
#define E_EDGES 1600000
#define ETOT    (E_EDGES + N_NODES)
#define IN_DIM  300
#define HID     256
#define HEADS   8
#define OC      32
#define LAYERS  4
#define BSAMP   1024
#define NCLS    3
#define NEG_SLOPE 0.2f

// ---------------------------------------------------------------- CSR build

__global__ __launch_bounds__(256) void init_counts_kernel(int* counts) {
    int i = blockIdx.x * 256 + threadIdx.x;
    if (i < N_NODES) counts[i] = 1;   // self loop pre-counted
}

__global__ __launch_bounds__(256) void count_edges_kernel(const int* __restrict__ tgt, int* counts) {
    int e = blockIdx.x * 256 + threadIdx.x;
    if (e < E_EDGES) atomicAdd(&counts[tgt[e]], 1);
}

// single-block exclusive scan of counts -> row_ptr[0..N], cursor copy
__global__ __launch_bounds__(256) void scan_kernel(const int* __restrict__ counts,
                                                   int* __restrict__ row_ptr,
                                                   int* __restrict__ cursor) {
    __shared__ int sums[256];
    const int CHUNK = (N_NODES + 255) / 256;   // 196
    int t = threadIdx.x;
    int beg = t * CHUNK;
    int fin = min(beg + CHUNK, N_NODES);
    int s = 0;
    for (int i = beg; i < fin; i++) s += counts[i];
    sums[t] = s;
    __syncthreads();
    // Hillis-Steele inclusive scan over 256 entries
    for (int off = 1; off < 256; off <<= 1) {
        int a = sums[t];
        int u = (t >= off) ? sums[t - off] : 0;
        __syncthreads();
        sums[t] = a + u;
        __syncthreads();
    }
    int running = sums[t] - s;   // exclusive prefix for this chunk
    for (int i = beg; i < fin; i++) {
        row_ptr[i] = running;
        cursor[i]  = running;
        running += counts[i];
    }
    if (t == 255) row_ptr[N_NODES] = sums[255];
}

__global__ __launch_bounds__(256) void fill_edges_kernel(const int* __restrict__ src,
                                                         const int* __restrict__ tgt,
                                                         int* cursor, int* __restrict__ col) {
    int e = blockIdx.x * 256 + threadIdx.x;
    if (e >= ETOT) return;
    int s_, t_;
    if (e < E_EDGES) { s_ = src[e]; t_ = tgt[e]; }
    else             { s_ = t_ = e - E_EDGES; }
    int pos = atomicAdd(&cursor[t_], 1);
    col[pos] = s_;
}

// ---------------------------------------------------------------- fp32 GEMM
// C[M, 256] = A[M, K] @ B[K, 256] (+bias). BM=BN=64, BK=16, 256 thr, 4x4 microtile.
__global__ __launch_bounds__(256) void gemm64_kernel(const float* __restrict__ A,
                                                     const float* __restrict__ B,
                                                     const float* __restrict__ bias,
                                                     float* __restrict__ C,
                                                     int M, int K, int addbias) {
    __shared__ float As[16][64];   // [k][m]
    __shared__ float Bs[16][64];   // [k][n]
    const int tid = threadIdx.x;
    const int m0 = blockIdx.x * 64;
    const int n0 = blockIdx.y * 64;
    const int tm = tid >> 4, tn = tid & 15;
    const int lam = tid >> 2;            // 0..63  (A row in tile)
    const int lak = (tid & 3) * 4;       // 0,4,8,12
    const int lbk = tid >> 4;            // 0..15  (B row in tile)
    const int lbn = (tid & 15) * 4;
    float acc[4][4] = {};

    for (int k0 = 0; k0 < K; k0 += 16) {
        float4 av = {0.f, 0.f, 0.f, 0.f};
        int kk = k0 + lak;
        if (m0 + lam < M) {
            if (kk + 3 < K) {
                av = *(const float4*)&A[(size_t)(m0 + lam) * K + kk];
            } else {
                float tmp[4] = {0.f, 0.f, 0.f, 0.f};
                for (int i = 0; i < 4; i++) if (kk + i < K) tmp[i] = A[(size_t)(m0 + lam) * K + kk + i];
                av = make_float4(tmp[0], tmp[1], tmp[2], tmp[3]);
            }
        }
        As[lak + 0][lam] = av.x;
        As[lak + 1][lam] = av.y;
        As[lak + 2][lam] = av.z;
        As[lak + 3][lam] = av.w;

        float4 bv = {0.f, 0.f, 0.f, 0.f};
        if (k0 + lbk < K) bv = *(const float4*)&B[(size_t)(k0 + lbk) * HID + n0 + lbn];
        *(float4*)&Bs[lbk][lbn] = bv;
        __syncthreads();

        #pragma unroll
        for (int k = 0; k < 16; k++) {
            float4 a4 = *(const float4*)&As[k][tm * 4];
            float4 b4 = *(const float4*)&Bs[k][tn * 4];
            float aa[4] = {a4.x, a4.y, a4.z, a4.w};
            float bb[4] = {b4.x, b4.y, b4.z, b4.w};
            #pragma unroll
            for (int i = 0; i < 4; i++)
                #pragma unroll
                for (int j = 0; j < 4; j++)
                    acc[i][j] += aa[i] * bb[j];
        }
        __syncthreads();
    }

    #pragma unroll
    for (int i = 0; i < 4; i++) {
        int m = m0 + tm * 4 + i;
        if (m < M) {
            int n = n0 + tn * 4;
            float4 o = make_float4(acc[i][0], acc[i][1], acc[i][2], acc[i][3]);
            if (addbias) { o.x += bias[n]; o.y += bias[n + 1]; o.z += bias[n + 2]; o.w += bias[n + 3]; }
            *(float4*)&C[(size_t)m * HID + n] = o;
        }
    }
}

// ---------------------------------------------------------------- attention scores
// s_dst[n,h] = sum_o hw[n,h,o]*att_dst[h,o];  same for src. One block per node.
__global__ __launch_bounds__(256) void score_kernel(const float* __restrict__ hw,
                                                    const float* __restrict__ att_dst,
                                                    const float* __restrict__ att_src,
                                                    float* __restrict__ s_dst,
                                                    float* __restrict__ s_src) {
    int n = blockIdx.x;
    int c = threadIdx.x;                 // channel 0..255, head = c>>5
    float v  = hw[(size_t)n * HID + c];
    float vd = v * att_dst[c];
    float vs = v * att_src[c];
    #pragma unroll
    for (int off = 16; off >= 1; off >>= 1) {
        vd += __shfl_xor(vd, off);
        vs += __shfl_xor(vs, off);
    }
    if ((c & 31) == 0) {
        int h = c >> 5;
        s_dst[(size_t)n * HEADS + h] = vd;
        s_src[(size_t)n * HEADS + h] = vs;
    }
}

// ---------------------------------------------------------------- aggregation
// One wave (64 lanes) per target node. Lane owns 4 channels (float4); head = lane>>3.
// Pass 1: per-head max of alpha. Pass 2: ex + denom + weighted sum, then /denom + bias + ELU.
__global__ __launch_bounds__(256) void agg_kernel(const int* __restrict__ row_ptr,
                                                  const int* __restrict__ col,
                                                  const float* __restrict__ s_dst,
                                                  const float* __restrict__ s_src,
                                                  const float4* __restrict__ hw4,
                                                  const float* __restrict__ bias,
                                                  float* __restrict__ h_out) {
    int wave = threadIdx.x >> 6;
    int lane = threadIdx.x & 63;
    int t = blockIdx.x * 4 + wave;
    if (t >= N_NODES) return;

    int start = row_ptr[t];
    int end   = row_ptr[t + 1];
    int eh  = lane & 7;       // head role for edge phase
    int ech = lane >> 3;      // edge slot 0..7
    int chead = lane >> 3;    // head of my channels (4*lane / 32)

    float sd = s_dst[(size_t)t * HEADS + eh];

    // pass 1: per-head max
    float mx = -1e30f;
    for (int base = start; base < end; base += 8) {
        int e = base + ech;
        if (e < end) {
            int sn = col[e];
            float a = sd + s_src[(size_t)sn * HEADS + eh];
            a = (a > 0.f) ? a : NEG_SLOPE * a;
            mx = fmaxf(mx, a);
        }
    }
    mx = fmaxf(mx, __shfl_xor(mx, 8));
    mx = fmaxf(mx, __shfl_xor(mx, 16));
    mx = fmaxf(mx, __shfl_xor(mx, 32));   // all lanes now hold max for head (lane&7)

    // pass 2: exp, denom, weighted aggregate
    float4 acc = {0.f, 0.f, 0.f, 0.f};
    float dsum = 0.f;
    for (int base = start; base < end; base += 8) {
        int e = base + ech;
        float exv = 0.f;
        int sn = 0;
        if (e < end) {
            sn = col[e];
            float a = sd + s_src[(size_t)sn * HEADS + eh];
            a = (a > 0.f) ? a : NEG_SLOPE * a;
            exv = __expf(a - mx);
            dsum += exv;
        }
        int cnt = min(8, end - base);
        for (int j = 0; j < cnt; j++) {
            float exj = __shfl(exv, j * 8 + chead);
            int  snj  = __shfl(sn,  j * 8);
            float4 v = hw4[(size_t)snj * 64 + lane];
            acc.x += exj * v.x;
            acc.y += exj * v.y;
            acc.z += exj * v.z;
            acc.w += exj * v.w;
        }
    }
    dsum += __shfl_xor(dsum, 8);
    dsum += __shfl_xor(dsum, 16);
    dsum += __shfl_xor(dsum, 32);
    float den = __shfl(dsum, chead) + 1e-16f;
    float inv = 1.f / den;

    int cb = lane * 4;
    float o[4] = {acc.x * inv + bias[cb + 0], acc.y * inv + bias[cb + 1],
                  acc.z * inv + bias[cb + 2], acc.w * inv + bias[cb + 3]};
    #pragma unroll
    for (int i = 0; i < 4; i++) o[i] = (o[i] > 0.f) ? o[i] : (__expf(o[i]) - 1.f);
    float4 ov = make_float4(o[0], o[1], o[2], o[3]);
    ((float4*)h_out)[(size_t)t * 64 + lane] = ov;
}

// ---------------------------------------------------------------- head: gather + lin3
__global__ __launch_bounds__(256) void head_kernel(const float* __restrict__ h,
                                                   const int* __restrict__ target_mask,
                                                   const float* __restrict__ W,
                                                   const float* __restrict__ b,
                                                   float* __restrict__ out) {
    int s = blockIdx.x;
    int t = threadIdx.x;
    int n0 = target_mask[s * 2 + 0];
    int n1 = target_mask[s * 2 + 1];
    float f0 = h[(size_t)n0 * HID + t];
    float f1 = h[(size_t)n1 * HID + t];
    float a0 = f0 * W[t * 3 + 0] + f1 * W[(t + 256) * 3 + 0];
    float a1 = f0 * W[t * 3 + 1] + f1 * W[(t + 256) * 3 + 1];
    float a2 = f0 * W[t * 3 + 2] + f1 * W[(t + 256) * 3 + 2];
    #pragma unroll
    for (int off = 32; off >= 1; off >>= 1) {
        a0 += __shfl_xor(a0, off);
        a1 += __shfl_xor(a1, off);
        a2 += __shfl_xor(a2, off);
    }
    __shared__ float red[4][3];
    int wv = t >> 6, ln = t & 63;
    if (ln == 0) { red[wv][0] = a0; red[wv][1] = a1; red[wv][2] = a2; }
    __syncthreads();
    if (t < 3) {
        float v = red[0][t] + red[1][t] + red[2][t] + red[3][t] + b[t];
        out[s * 3 + t] = v;
    }
}

// ---------------------------------------------------------------- launch

extern "C" void kernel_launch(void* const* d_in, const int* in_sizes, int n_in,
                              void* d_out, int out_size, void* d_ws, size_t ws_size,
                              hipStream_t stream) {
    const float* x        = (const float*)d_in[0];
    const int*   eidx     = (const int*)  d_in[1];
    const int*   tmask    = (const int*)  d_in[2];
    const float* lin1_W   = (const float*)d_in[3];
    const float* lin1_b   = (const float*)d_in[4];
    const float* convs_W  = (const float*)d_in[5];
    const float* att_dst  = (const float*)d_in[6];
    const float* att_src  = (const float*)d_in[7];
    const float* convs_b  = (const float*)d_in[8];
    const float* lin3_W   = (const float*)d_in[9];
    const float* lin3_b   = (const float*)d_in[10];
    float* out = (float*)d_out;

    char* ws = (char*)d_ws;
    size_t off = 0;
    auto alloc = [&](size_t bytes) -> void* {
        void* p = ws + off;
        off = (off + bytes + 255) & ~(size_t)255;
        return p;
    };
    float* h      = (float*)alloc((size_t)N_NODES * HID * 4);
    float* hw     = (float*)alloc((size_t)N_NODES * HID * 4);
    float* sdst   = (float*)alloc((size_t)N_NODES * HEADS * 4);
    float* ssrc   = (float*)alloc((size_t)N_NODES * HEADS * 4);
    int*   counts = (int*)  alloc((size_t)N_NODES * 4);
    int*   rowptr = (int*)  alloc((size_t)(N_NODES + 1) * 4);
    int*   cursor = (int*)  alloc((size_t)N_NODES * 4);
    int*   col    = (int*)  alloc((size_t)ETOT * 4);

    const int* src = eidx;            // edge_index[0]
    const int* tgt = eidx + E_EDGES;  // edge_index[1]

    // CSR build (shared by all 4 layers)
    init_counts_kernel<<<(N_NODES + 255) / 256, 256, 0, stream>>>(counts);
    count_edges_kernel<<<(E_EDGES + 255) / 256, 256, 0, stream>>>(tgt, counts);
    scan_kernel<<<1, 256, 0, stream>>>(counts, rowptr, cursor);
    fill_edges_kernel<<<(ETOT + 255) / 256, 256, 0, stream>>>(src, tgt, cursor, col);

    // lin1
    gemm64_kernel<<<dim3((N_NODES + 63) / 64, HID / 64), 256, 0, stream>>>(
        x, lin1_W, lin1_b, h, N_NODES, IN_DIM, 1);

    for (int l = 0; l < LAYERS; l++) {
        gemm64_kernel<<<dim3((N_NODES + 63) / 64, HID / 64), 256, 0, stream>>>(
            h, convs_W + (size_t)l * HID * HID, nullptr, hw, N_NODES, HID, 0);
        score_kernel<<<N_NODES, 256, 0, stream>>>(
            hw, att_dst + (size_t)l * HEADS * OC, att_src + (size_t)l * HEADS * OC, sdst, ssrc);
        agg_kernel<<<(N_NODES + 3) / 4, 256, 0, stream>>>(
            rowptr, col, sdst, ssrc, (const float4*)hw, convs_b + (size_t)l * HID, h);
    }

    head_kernel<<<BSAMP, 256, 0, stream>>>(h, tmask, lin3_W, lin3_b, out);
}

// Round 2
// 1326.062 us; speedup vs baseline: 1.5419x; 1.5419x over previous
//
#include <hip/hip_runtime.h>
#include <math.h>

#define N_NODES 50000
#define N_PAD   50048            // padded rows for 128-row GEMM tiles
#define E_EDGES 1600000
#define ETOT    (E_EDGES + N_NODES)
#define IN_DIM  300
#define KP1     320              // IN_DIM padded to mult of 32
#define HID     256
#define HEADS   8
#define OC      32
#define LAYERS  4
#define BSAMP   1024
#define NEG_SLOPE 0.2f

typedef _Float16 half8 __attribute__((ext_vector_type(8)));
typedef _Float16 half4v __attribute__((ext_vector_type(4)));
typedef float f32x4 __attribute__((ext_vector_type(4)));

// ---------------------------------------------------------------- CSR build

__global__ __launch_bounds__(256) void init_counts_kernel(int* counts) {
    int i = blockIdx.x * 256 + threadIdx.x;
    if (i < N_NODES) counts[i] = 1;   // self loop pre-counted
}

__global__ __launch_bounds__(256) void count_edges_kernel(const int* __restrict__ tgt, int* counts) {
    int e = blockIdx.x * 256 + threadIdx.x;
    if (e < E_EDGES) atomicAdd(&counts[tgt[e]], 1);
}

__global__ __launch_bounds__(256) void scan_kernel(const int* __restrict__ counts,
                                                   int* __restrict__ row_ptr,
                                                   int* __restrict__ cursor) {
    __shared__ int sums[256];
    const int CHUNK = (N_NODES + 255) / 256;
    int t = threadIdx.x;
    int beg = t * CHUNK;
    int fin = min(beg + CHUNK, N_NODES);
    int s = 0;
    for (int i = beg; i < fin; i++) s += counts[i];
    sums[t] = s;
    __syncthreads();
    for (int off = 1; off < 256; off <<= 1) {
        int a = sums[t];
        int u = (t >= off) ? sums[t - off] : 0;
        __syncthreads();
        sums[t] = a + u;
        __syncthreads();
    }
    int running = sums[t] - s;
    for (int i = beg; i < fin; i++) {
        row_ptr[i] = running;
        cursor[i]  = running;
        running += counts[i];
    }
    if (t == 255) row_ptr[N_NODES] = sums[255];
}

__global__ __launch_bounds__(256) void fill_edges_kernel(const int* __restrict__ src,
                                                         const int* __restrict__ tgt,
                                                         int* cursor, int* __restrict__ col) {
    int e = blockIdx.x * 256 + threadIdx.x;
    if (e >= ETOT) return;
    int s_, t_;
    if (e < E_EDGES) { s_ = src[e]; t_ = tgt[e]; }
    else             { s_ = t_ = e - E_EDGES; }
    int pos = atomicAdd(&cursor[t_], 1);
    col[pos] = s_;
}

// ---------------------------------------------------------------- fp32 -> fp16 casts

// x [N, 300] fp32 -> x_h [N_PAD, 320] fp16 (zero-pad cols; rows >= N left as-is)
__global__ __launch_bounds__(256) void cast_x_kernel(const float* __restrict__ x, _Float16* __restrict__ xh) {
    long i = (long)blockIdx.x * 256 + threadIdx.x;
    if (i >= (long)N_NODES * KP1) return;
    int r = (int)(i / KP1), c = (int)(i % KP1);
    float v = (c < IN_DIM) ? x[(size_t)r * IN_DIM + c] : 0.f;
    xh[i] = (_Float16)v;
}

// lin1_W [300,256] -> w1t [256][320] fp16 transposed, zero-padded
__global__ __launch_bounds__(256) void cast_w1_kernel(const float* __restrict__ W, _Float16* __restrict__ Wt) {
    int i = blockIdx.x * 256 + threadIdx.x;   // over 256*320
    if (i >= HID * KP1) return;
    int n = i / KP1, k = i % KP1;
    float v = (k < IN_DIM) ? W[(size_t)k * HID + n] : 0.f;
    Wt[i] = (_Float16)v;
}

// convs_W [4,256,256] -> wct [4][256][256] fp16 transposed per layer
__global__ __launch_bounds__(256) void cast_wc_kernel(const float* __restrict__ W, _Float16* __restrict__ Wt) {
    int i = blockIdx.x * 256 + threadIdx.x;   // over 4*256*256
    if (i >= LAYERS * HID * HID) return;
    int l = i / (HID * HID);
    int r = i % (HID * HID);
    int n = r / HID, k = r % HID;
    Wt[i] = (_Float16)W[(size_t)l * HID * HID + (size_t)k * HID + n];
}

// ---------------------------------------------------------------- fp16 MFMA GEMM
// C[M,256] = A[M,Kp] @ Wt^T  (Wt is [256][Kp], i.e. B[k][n]=Wt[n][k]), fp32 acc.
// Tile 128x128, BK=32, 256 threads = 4 waves, each wave 64x64 (4x4 MFMA 16x16x32).
__global__ __launch_bounds__(256) void gemm_mfma_kernel(const _Float16* __restrict__ A,
                                                        const _Float16* __restrict__ Wt,
                                                        const float* __restrict__ bias,
                                                        _Float16* __restrict__ C,
                                                        int M, int Kp, int addbias) {
    __shared__ _Float16 As[128][32];
    __shared__ _Float16 Bs[128][32];   // row = n (within 128-col tile), col = k
    const int tid = threadIdx.x;
    const int m0 = blockIdx.x * 128;
    const int n0 = blockIdx.y * 128;
    const int w = tid >> 6, lane = tid & 63;
    const int wm = (w & 1) * 64, wn = (w >> 1) * 64;
    const int quad = lane >> 4, m16 = lane & 15;

    f32x4 acc[4][4];
    #pragma unroll
    for (int i = 0; i < 4; i++)
        #pragma unroll
        for (int j = 0; j < 4; j++)
            acc[i][j] = (f32x4){0.f, 0.f, 0.f, 0.f};

    for (int k0 = 0; k0 < Kp; k0 += 32) {
        // stage A: 128 rows x 32 halves = 512 x 16B segments; 256 thr x 2
        #pragma unroll
        for (int i = 0; i < 2; i++) {
            int seg = tid + i * 256;
            int row = seg >> 2, off = seg & 3;
            uint4 v = *(const uint4*)&A[(size_t)(m0 + row) * Kp + k0 + off * 8];
            *(uint4*)&As[row][off * 8] = v;
            uint4 u = *(const uint4*)&Wt[(size_t)(n0 + row) * Kp + k0 + off * 8];
            *(uint4*)&Bs[row][off * 8] = u;
        }
        __syncthreads();

        half8 af[4], bf[4];
        #pragma unroll
        for (int i = 0; i < 4; i++) {
            af[i] = *(const half8*)&As[wm + i * 16 + m16][quad * 8];
            bf[i] = *(const half8*)&Bs[wn + i * 16 + m16][quad * 8];
        }
        #pragma unroll
        for (int mi = 0; mi < 4; mi++)
            #pragma unroll
            for (int ni = 0; ni < 4; ni++)
                acc[mi][ni] = __builtin_amdgcn_mfma_f32_16x16x32_f16(af[mi], bf[ni], acc[mi][ni], 0, 0, 0);
        __syncthreads();
    }

    #pragma unroll
    for (int mi = 0; mi < 4; mi++) {
        #pragma unroll
        for (int r = 0; r < 4; r++) {
            int row = m0 + wm + mi * 16 + quad * 4 + r;
            if (row < M) {
                #pragma unroll
                for (int ni = 0; ni < 4; ni++) {
                    int colg = n0 + wn + ni * 16 + m16;
                    float v = acc[mi][ni][r];
                    if (addbias) v += bias[colg];
                    C[(size_t)row * HID + colg] = (_Float16)v;
                }
            }
        }
    }
}

// ---------------------------------------------------------------- attention scores
__global__ __launch_bounds__(256) void score_kernel(const _Float16* __restrict__ hw,
                                                    const float* __restrict__ att_dst,
                                                    const float* __restrict__ att_src,
                                                    float* __restrict__ s_dst,
                                                    float* __restrict__ s_src) {
    int n = blockIdx.x;
    int c = threadIdx.x;
    float v  = (float)hw[(size_t)n * HID + c];
    float vd = v * att_dst[c];
    float vs = v * att_src[c];
    #pragma unroll
    for (int off = 16; off >= 1; off >>= 1) {
        vd += __shfl_xor(vd, off);
        vs += __shfl_xor(vs, off);
    }
    if ((c & 31) == 0) {
        int h = c >> 5;
        s_dst[(size_t)n * HEADS + h] = vd;
        s_src[(size_t)n * HEADS + h] = vs;
    }
}

// ---------------------------------------------------------------- aggregation (fp16 gather)
__global__ __launch_bounds__(256) void agg_kernel(const int* __restrict__ row_ptr,
                                                  const int* __restrict__ col,
                                                  const float* __restrict__ s_dst,
                                                  const float* __restrict__ s_src,
                                                  const _Float16* __restrict__ hw,
                                                  const float* __restrict__ bias,
                                                  _Float16* __restrict__ h_out) {
    int wave = threadIdx.x >> 6;
    int lane = threadIdx.x & 63;
    int t = blockIdx.x * 4 + wave;
    if (t >= N_NODES) return;

    int start = row_ptr[t];
    int end   = row_ptr[t + 1];
    int eh  = lane & 7;
    int ech = lane >> 3;
    int chead = lane >> 3;

    float sd = s_dst[(size_t)t * HEADS + eh];

    // pass 1: per-head max
    float mx = -1e30f;
    for (int base = start; base < end; base += 8) {
        int e = base + ech;
        if (e < end) {
            int sn = col[e];
            float a = sd + s_src[(size_t)sn * HEADS + eh];
            a = (a > 0.f) ? a : NEG_SLOPE * a;
            mx = fmaxf(mx, a);
        }
    }
    mx = fmaxf(mx, __shfl_xor(mx, 8));
    mx = fmaxf(mx, __shfl_xor(mx, 16));
    mx = fmaxf(mx, __shfl_xor(mx, 32));

    // pass 2: exp, denom, weighted aggregate
    float4 acc = {0.f, 0.f, 0.f, 0.f};
    float dsum = 0.f;
    const half4v* hw4 = (const half4v*)hw;
    for (int base = start; base < end; base += 8) {
        int e = base + ech;
        float exv = 0.f;
        int sn = 0;
        if (e < end) {
            sn = col[e];
            float a = sd + s_src[(size_t)sn * HEADS + eh];
            a = (a > 0.f) ? a : NEG_SLOPE * a;
            exv = __expf(a - mx);
            dsum += exv;
        }
        int cnt = min(8, end - base);
        for (int j = 0; j < cnt; j++) {
            float exj = __shfl(exv, j * 8 + chead);
            int  snj  = __shfl(sn,  j * 8);
            half4v v = hw4[(size_t)snj * 64 + lane];
            acc.x += exj * (float)v[0];
            acc.y += exj * (float)v[1];
            acc.z += exj * (float)v[2];
            acc.w += exj * (float)v[3];
        }
    }
    dsum += __shfl_xor(dsum, 8);
    dsum += __shfl_xor(dsum, 16);
    dsum += __shfl_xor(dsum, 32);
    float den = __shfl(dsum, chead) + 1e-16f;
    float inv = 1.f / den;

    int cb = lane * 4;
    float o[4] = {acc.x * inv + bias[cb + 0], acc.y * inv + bias[cb + 1],
                  acc.z * inv + bias[cb + 2], acc.w * inv + bias[cb + 3]};
    #pragma unroll
    for (int i = 0; i < 4; i++) o[i] = (o[i] > 0.f) ? o[i] : (__expf(o[i]) - 1.f);
    half4v ov;
    ov[0] = (_Float16)o[0]; ov[1] = (_Float16)o[1];
    ov[2] = (_Float16)o[2]; ov[3] = (_Float16)o[3];
    ((half4v*)h_out)[(size_t)t * 64 + lane] = ov;
}

// ---------------------------------------------------------------- head
__global__ __launch_bounds__(256) void head_kernel(const _Float16* __restrict__ h,
                                                   const int* __restrict__ target_mask,
                                                   const float* __restrict__ W,
                                                   const float* __restrict__ b,
                                                   float* __restrict__ out) {
    int s = blockIdx.x;
    int t = threadIdx.x;
    int n0 = target_mask[s * 2 + 0];
    int n1 = target_mask[s * 2 + 1];
    float f0 = (float)h[(size_t)n0 * HID + t];
    float f1 = (float)h[(size_t)n1 * HID + t];
    float a0 = f0 * W[t * 3 + 0] + f1 * W[(t + 256) * 3 + 0];
    float a1 = f0 * W[t * 3 + 1] + f1 * W[(t + 256) * 3 + 1];
    float a2 = f0 * W[t * 3 + 2] + f1 * W[(t + 256) * 3 + 2];
    #pragma unroll
    for (int off = 32; off >= 1; off >>= 1) {
        a0 += __shfl_xor(a0, off);
        a1 += __shfl_xor(a1, off);
        a2 += __shfl_xor(a2, off);
    }
    __shared__ float red[4][3];
    int wv = t >> 6, ln = t & 63;
    if (ln == 0) { red[wv][0] = a0; red[wv][1] = a1; red[wv][2] = a2; }
    __syncthreads();
    if (t < 3) {
        out[s * 3 + t] = red[0][t] + red[1][t] + red[2][t] + red[3][t] + b[t];
    }
}

// ---------------------------------------------------------------- launch

extern "C" void kernel_launch(void* const* d_in, const int* in_sizes, int n_in,
                              void* d_out, int out_size, void* d_ws, size_t ws_size,
                              hipStream_t stream) {
    const float* x        = (const float*)d_in[0];
    const int*   eidx     = (const int*)  d_in[1];
    const int*   tmask    = (const int*)  d_in[2];
    const float* lin1_W   = (const float*)d_in[3];
    const float* lin1_b   = (const float*)d_in[4];
    const float* convs_W  = (const float*)d_in[5];
    const float* att_dst  = (const float*)d_in[6];
    const float* att_src  = (const float*)d_in[7];
    const float* convs_b  = (const float*)d_in[8];
    const float* lin3_W   = (const float*)d_in[9];
    const float* lin3_b   = (const float*)d_in[10];
    float* out = (float*)d_out;

    char* ws = (char*)d_ws;
    size_t off = 0;
    auto alloc = [&](size_t bytes) -> void* {
        void* p = ws + off;
        off = (off + bytes + 255) & ~(size_t)255;
        return p;
    };
    _Float16* xh   = (_Float16*)alloc((size_t)N_PAD * KP1 * 2);
    _Float16* h    = (_Float16*)alloc((size_t)N_PAD * HID * 2);
    _Float16* hw   = (_Float16*)alloc((size_t)N_NODES * HID * 2);
    _Float16* w1t  = (_Float16*)alloc((size_t)HID * KP1 * 2);
    _Float16* wct  = (_Float16*)alloc((size_t)LAYERS * HID * HID * 2);
    float* sdst    = (float*)alloc((size_t)N_NODES * HEADS * 4);
    float* ssrc    = (float*)alloc((size_t)N_NODES * HEADS * 4);
    int*   counts  = (int*)  alloc((size_t)N_NODES * 4);
    int*   rowptr  = (int*)  alloc((size_t)(N_NODES + 1) * 4);
    int*   cursor  = (int*)  alloc((size_t)N_NODES * 4);
    int*   col     = (int*)  alloc((size_t)ETOT * 4);

    const int* src = eidx;
    const int* tgt = eidx + E_EDGES;

    // CSR build (shared by all 4 layers)
    init_counts_kernel<<<(N_NODES + 255) / 256, 256, 0, stream>>>(counts);
    count_edges_kernel<<<(E_EDGES + 255) / 256, 256, 0, stream>>>(tgt, counts);
    scan_kernel<<<1, 256, 0, stream>>>(counts, rowptr, cursor);
    fill_edges_kernel<<<(ETOT + 255) / 256, 256, 0, stream>>>(src, tgt, cursor, col);

    // casts
    cast_x_kernel<<<((long)N_NODES * KP1 + 255) / 256, 256, 0, stream>>>(x, xh);
    cast_w1_kernel<<<(HID * KP1 + 255) / 256, 256, 0, stream>>>(lin1_W, w1t);
    cast_wc_kernel<<<(LAYERS * HID * HID + 255) / 256, 256, 0, stream>>>(convs_W, wct);

    // lin1
    gemm_mfma_kernel<<<dim3((N_NODES + 127) / 128, HID / 128), 256, 0, stream>>>(
        xh, w1t, lin1_b, h, N_NODES, KP1, 1);

    for (int l = 0; l < LAYERS; l++) {
        gemm_mfma_kernel<<<dim3((N_NODES + 127) / 128, HID / 128), 256, 0, stream>>>(
            h, wct + (size_t)l * HID * HID, nullptr, hw, N_NODES, HID, 0);
        score_kernel<<<N_NODES, 256, 0, stream>>>(
            hw, att_dst + (size_t)l * HEADS * OC, att_src + (size_t)l * HEADS * OC, sdst, ssrc);
        agg_kernel<<<(N_NODES + 3) / 4, 256, 0, stream>>>(
            rowptr, col, sdst, ssrc, hw, convs_b + (size_t)l * HID, h);
    }

    head_kernel<<<BSAMP, 256, 0, stream>>>(h, tmask, lin3_W, lin3_b, out);
}

// Round 3
// 1173.500 us; speedup vs baseline: 1.7424x; 1.1300x over previous
//
#include <hip/hip_runtime.h>
#include <math.h>

#define N_NODES 50000
#define N_PAD   50048            // padded rows for 128-row GEMM tiles
#define E_EDGES 1600000
#define ETOT    (E_EDGES + N_NODES)
#define EPAD    (E_EDGES + 8 * N_NODES)   // CSR rows padded to multiple of 8
#define IN_DIM  300
#define KP1     320              // IN_DIM padded to mult of 32
#define HID     256
#define HEADS   8
#define OC      32
#define LAYERS  4
#define BSAMP   1024
#define NEG_SLOPE 0.2f
#define DEG_CAP 128              // fast-path max padded degree per node

typedef _Float16 half8 __attribute__((ext_vector_type(8)));
typedef _Float16 half4v __attribute__((ext_vector_type(4)));
typedef float f32x4 __attribute__((ext_vector_type(4)));

// ---------------------------------------------------------------- CSR build

__global__ __launch_bounds__(256) void init_counts_kernel(int* counts) {
    int i = blockIdx.x * 256 + threadIdx.x;
    if (i < N_NODES) counts[i] = 1;   // self loop pre-counted
}

__global__ __launch_bounds__(256) void count_edges_kernel(const int* __restrict__ tgt, int* counts) {
    int e = blockIdx.x * 256 + threadIdx.x;
    if (e < E_EDGES) atomicAdd(&counts[tgt[e]], 1);
}

// exclusive scan of PADDED counts -> row_ptr (padded starts), cursor copy
__global__ __launch_bounds__(256) void scan_kernel(const int* __restrict__ counts,
                                                   int* __restrict__ row_ptr,
                                                   int* __restrict__ cursor) {
    __shared__ int sums[256];
    const int CHUNK = (N_NODES + 255) / 256;
    int t = threadIdx.x;
    int beg = t * CHUNK;
    int fin = min(beg + CHUNK, N_NODES);
    int s = 0;
    for (int i = beg; i < fin; i++) s += (counts[i] + 7) & ~7;
    sums[t] = s;
    __syncthreads();
    for (int off = 1; off < 256; off <<= 1) {
        int a = sums[t];
        int u = (t >= off) ? sums[t - off] : 0;
        __syncthreads();
        sums[t] = a + u;
        __syncthreads();
    }
    int running = sums[t] - s;
    for (int i = beg; i < fin; i++) {
        row_ptr[i] = running;
        cursor[i]  = running;
        running += (counts[i] + 7) & ~7;
    }
    if (t == 255) row_ptr[N_NODES] = sums[255];
}

__global__ __launch_bounds__(256) void fill_edges_kernel(const int* __restrict__ src,
                                                         const int* __restrict__ tgt,
                                                         int* cursor, int* __restrict__ col) {
    int e = blockIdx.x * 256 + threadIdx.x;
    if (e >= ETOT) return;
    int s_, t_;
    if (e < E_EDGES) { s_ = src[e]; t_ = tgt[e]; }
    else             { s_ = t_ = e - E_EDGES; }
    int pos = atomicAdd(&cursor[t_], 1);
    col[pos] = s_;
}

// fill pad slots with the row's own node id (valid index; masked out later)
__global__ __launch_bounds__(256) void pad_edges_kernel(const int* __restrict__ cursor,
                                                        const int* __restrict__ row_ptr,
                                                        int* __restrict__ col) {
    int i = blockIdx.x * 256 + threadIdx.x;
    if (i >= N_NODES) return;
    int e = cursor[i];            // true end after fill
    int pe = row_ptr[i + 1];      // padded end
    for (; e < pe; e++) col[e] = i;
}

// ---------------------------------------------------------------- fp32 -> fp16 casts

__global__ __launch_bounds__(256) void cast_x_kernel(const float* __restrict__ x, _Float16* __restrict__ xh) {
    long i = (long)blockIdx.x * 256 + threadIdx.x;
    if (i >= (long)N_NODES * KP1) return;
    int r = (int)(i / KP1), c = (int)(i % KP1);
    float v = (c < IN_DIM) ? x[(size_t)r * IN_DIM + c] : 0.f;
    xh[i] = (_Float16)v;
}

__global__ __launch_bounds__(256) void cast_w1_kernel(const float* __restrict__ W, _Float16* __restrict__ Wt) {
    int i = blockIdx.x * 256 + threadIdx.x;
    if (i >= HID * KP1) return;
    int n = i / KP1, k = i % KP1;
    float v = (k < IN_DIM) ? W[(size_t)k * HID + n] : 0.f;
    Wt[i] = (_Float16)v;
}

__global__ __launch_bounds__(256) void cast_wc_kernel(const float* __restrict__ W, _Float16* __restrict__ Wt) {
    int i = blockIdx.x * 256 + threadIdx.x;
    if (i >= LAYERS * HID * HID) return;
    int l = i / (HID * HID);
    int r = i % (HID * HID);
    int n = r / HID, k = r % HID;
    Wt[i] = (_Float16)W[(size_t)l * HID * HID + (size_t)k * HID + n];
}

// ---------------------------------------------------------------- fp16 MFMA GEMM
__global__ __launch_bounds__(256) void gemm_mfma_kernel(const _Float16* __restrict__ A,
                                                        const _Float16* __restrict__ Wt,
                                                        const float* __restrict__ bias,
                                                        _Float16* __restrict__ C,
                                                        int M, int Kp, int addbias) {
    __shared__ _Float16 As[128][32];
    __shared__ _Float16 Bs[128][32];
    const int tid = threadIdx.x;
    const int m0 = blockIdx.x * 128;
    const int n0 = blockIdx.y * 128;
    const int w = tid >> 6, lane = tid & 63;
    const int wm = (w & 1) * 64, wn = (w >> 1) * 64;
    const int quad = lane >> 4, m16 = lane & 15;

    f32x4 acc[4][4];
    #pragma unroll
    for (int i = 0; i < 4; i++)
        #pragma unroll
        for (int j = 0; j < 4; j++)
            acc[i][j] = (f32x4){0.f, 0.f, 0.f, 0.f};

    for (int k0 = 0; k0 < Kp; k0 += 32) {
        #pragma unroll
        for (int i = 0; i < 2; i++) {
            int seg = tid + i * 256;
            int row = seg >> 2, off = seg & 3;
            uint4 v = *(const uint4*)&A[(size_t)(m0 + row) * Kp + k0 + off * 8];
            *(uint4*)&As[row][off * 8] = v;
            uint4 u = *(const uint4*)&Wt[(size_t)(n0 + row) * Kp + k0 + off * 8];
            *(uint4*)&Bs[row][off * 8] = u;
        }
        __syncthreads();

        half8 af[4], bf[4];
        #pragma unroll
        for (int i = 0; i < 4; i++) {
            af[i] = *(const half8*)&As[wm + i * 16 + m16][quad * 8];
            bf[i] = *(const half8*)&Bs[wn + i * 16 + m16][quad * 8];
        }
        #pragma unroll
        for (int mi = 0; mi < 4; mi++)
            #pragma unroll
            for (int ni = 0; ni < 4; ni++)
                acc[mi][ni] = __builtin_amdgcn_mfma_f32_16x16x32_f16(af[mi], bf[ni], acc[mi][ni], 0, 0, 0);
        __syncthreads();
    }

    #pragma unroll
    for (int mi = 0; mi < 4; mi++) {
        #pragma unroll
        for (int r = 0; r < 4; r++) {
            int row = m0 + wm + mi * 16 + quad * 4 + r;
            if (row < M) {
                #pragma unroll
                for (int ni = 0; ni < 4; ni++) {
                    int colg = n0 + wn + ni * 16 + m16;
                    float v = acc[mi][ni][r];
                    if (addbias) v += bias[colg];
                    C[(size_t)row * HID + colg] = (_Float16)v;
                }
            }
        }
    }
}

// ---------------------------------------------------------------- attention scores
__global__ __launch_bounds__(256) void score_kernel(const _Float16* __restrict__ hw,
                                                    const float* __restrict__ att_dst,
                                                    const float* __restrict__ att_src,
                                                    float* __restrict__ s_dst,
                                                    float* __restrict__ s_src) {
    int n = blockIdx.x;
    int c = threadIdx.x;
    float v  = (float)hw[(size_t)n * HID + c];
    float vd = v * att_dst[c];
    float vs = v * att_src[c];
    #pragma unroll
    for (int off = 16; off >= 1; off >>= 1) {
        vd += __shfl_xor(vd, off);
        vs += __shfl_xor(vs, off);
    }
    if ((c & 31) == 0) {
        int h = c >> 5;
        s_dst[(size_t)n * HEADS + h] = vd;
        s_src[(size_t)n * HEADS + h] = vs;
    }
}

// ---------------------------------------------------------------- aggregation
// Wave per target. Phase A: gather col + s_src once, alpha -> LDS, running max.
// Phase C: lanes = (parity p = lane>>5, channel-group c = lane&31, 8 ch each);
// 2 edges per 1KB wave-load (16B/lane), exp from LDS, no shuffles in hot loop.
__global__ __launch_bounds__(256) void agg_kernel(const int* __restrict__ row_ptr,
                                                  const int* __restrict__ deg_arr,
                                                  const int* __restrict__ col,
                                                  const float* __restrict__ s_dst,
                                                  const float* __restrict__ s_src,
                                                  const _Float16* __restrict__ hw,
                                                  const float* __restrict__ bias,
                                                  _Float16* __restrict__ h_out) {
    __shared__ float aL[4][DEG_CAP * 8];
    __shared__ int  snL[4][DEG_CAP];

    int wv   = threadIdx.x >> 6;
    int lane = threadIdx.x & 63;
    int t = blockIdx.x * 4 + wv;
    if (t >= N_NODES) return;

    int start = row_ptr[t];
    int pdeg  = row_ptr[t + 1] - start;
    int deg   = deg_arr[t];

    int eh  = lane & 7;        // head (phase A)
    int ech = lane >> 3;       // edge slot within group (phase A)
    float sd = s_dst[(size_t)t * HEADS + eh];

    if (pdeg <= DEG_CAP) {
        // ---------- fast path ----------
        // Phase A: alpha -> LDS, running per-head max
        float mx = -1e30f;
        int ngrp = pdeg >> 3;
        for (int g = 0; g < ngrp; g++) {
            int slot = g * 8 + ech;
            int sn = col[start + slot];
            float a = sd + s_src[(size_t)sn * HEADS + eh];
            a = (a > 0.f) ? a : NEG_SLOPE * a;
            aL[wv][slot * 8 + eh] = a;
            if (eh == 0) snL[wv][slot] = sn;
            if (slot < deg) mx = fmaxf(mx, a);
        }
        mx = fmaxf(mx, __shfl_xor(mx, 8));
        mx = fmaxf(mx, __shfl_xor(mx, 16));
        mx = fmaxf(mx, __shfl_xor(mx, 32));   // lanes with eh==h hold max_h

        // Phase C setup
        int p  = lane >> 5;          // edge parity
        int c  = lane & 31;          // channel group (8 channels)
        int hh = c >> 2;             // head of my channels
        float mxc = __shfl(mx, hh);  // lane hh has eh==hh

        const half8* hw8 = (const half8*)hw;
        float acc[8] = {0.f, 0.f, 0.f, 0.f, 0.f, 0.f, 0.f, 0.f};
        float dsum = 0.f;

        for (int g = 0; g < ngrp; g++) {
            int base = g * 8;
            int   sns[4];
            half8 v[4];
            float ex[4];
            #pragma unroll
            for (int j = 0; j < 4; j++) sns[j] = snL[wv][base + 2 * j + p];
            #pragma unroll
            for (int j = 0; j < 4; j++) v[j] = hw8[(size_t)sns[j] * 32 + c];
            #pragma unroll
            for (int j = 0; j < 4; j++) {
                int slot = base + 2 * j + p;
                float a = aL[wv][slot * 8 + hh];
                ex[j] = (slot < deg) ? __expf(a - mxc) : 0.f;
                dsum += ex[j];
            }
            #pragma unroll
            for (int j = 0; j < 4; j++)
                #pragma unroll
                for (int i = 0; i < 8; i++)
                    acc[i] += ex[j] * (float)v[j][i];
        }

        dsum += __shfl_xor(dsum, 32);
        #pragma unroll
        for (int i = 0; i < 8; i++) acc[i] += __shfl_xor(acc[i], 32);

        float inv = 1.f / (dsum + 1e-16f);
        if (p == 0) {
            half8 ov;
            #pragma unroll
            for (int i = 0; i < 8; i++) {
                float o = acc[i] * inv + bias[c * 8 + i];
                o = (o > 0.f) ? o : (__expf(o) - 1.f);
                ov[i] = (_Float16)o;
            }
            ((half8*)h_out)[(size_t)t * 32 + c] = ov;
        }
    } else {
        // ---------- slow path (pdeg > DEG_CAP; statistically never) ----------
        int end = start + deg;
        float mx = -1e30f;
        for (int base = start; base < end; base += 8) {
            int e = base + ech;
            if (e < end) {
                int sn = col[e];
                float a = sd + s_src[(size_t)sn * HEADS + eh];
                a = (a > 0.f) ? a : NEG_SLOPE * a;
                mx = fmaxf(mx, a);
            }
        }
        mx = fmaxf(mx, __shfl_xor(mx, 8));
        mx = fmaxf(mx, __shfl_xor(mx, 16));
        mx = fmaxf(mx, __shfl_xor(mx, 32));

        float4 acc = {0.f, 0.f, 0.f, 0.f};
        float dsum = 0.f;
        const half4v* hw4 = (const half4v*)hw;
        int chead = lane >> 3;
        for (int base = start; base < end; base += 8) {
            int e = base + ech;
            float exv = 0.f;
            int sn = 0;
            if (e < end) {
                sn = col[e];
                float a = sd + s_src[(size_t)sn * HEADS + eh];
                a = (a > 0.f) ? a : NEG_SLOPE * a;
                exv = __expf(a - mx);
                dsum += exv;
            }
            int cnt = min(8, end - base);
            for (int j = 0; j < cnt; j++) {
                float exj = __shfl(exv, j * 8 + chead);
                int  snj  = __shfl(sn,  j * 8);
                half4v v = hw4[(size_t)snj * 64 + lane];
                acc.x += exj * (float)v[0];
                acc.y += exj * (float)v[1];
                acc.z += exj * (float)v[2];
                acc.w += exj * (float)v[3];
            }
        }
        dsum += __shfl_xor(dsum, 8);
        dsum += __shfl_xor(dsum, 16);
        dsum += __shfl_xor(dsum, 32);
        float den = __shfl(dsum, chead) + 1e-16f;
        float inv = 1.f / den;
        int cb = lane * 4;
        float o[4] = {acc.x * inv + bias[cb + 0], acc.y * inv + bias[cb + 1],
                      acc.z * inv + bias[cb + 2], acc.w * inv + bias[cb + 3]};
        #pragma unroll
        for (int i = 0; i < 4; i++) o[i] = (o[i] > 0.f) ? o[i] : (__expf(o[i]) - 1.f);
        half4v ov;
        ov[0] = (_Float16)o[0]; ov[1] = (_Float16)o[1];
        ov[2] = (_Float16)o[2]; ov[3] = (_Float16)o[3];
        ((half4v*)h_out)[(size_t)t * 64 + lane] = ov;
    }
}

// ---------------------------------------------------------------- head
__global__ __launch_bounds__(256) void head_kernel(const _Float16* __restrict__ h,
                                                   const int* __restrict__ target_mask,
                                                   const float* __restrict__ W,
                                                   const float* __restrict__ b,
                                                   float* __restrict__ out) {
    int s = blockIdx.x;
    int t = threadIdx.x;
    int n0 = target_mask[s * 2 + 0];
    int n1 = target_mask[s * 2 + 1];
    float f0 = (float)h[(size_t)n0 * HID + t];
    float f1 = (float)h[(size_t)n1 * HID + t];
    float a0 = f0 * W[t * 3 + 0] + f1 * W[(t + 256) * 3 + 0];
    float a1 = f0 * W[t * 3 + 1] + f1 * W[(t + 256) * 3 + 1];
    float a2 = f0 * W[t * 3 + 2] + f1 * W[(t + 256) * 3 + 2];
    #pragma unroll
    for (int off = 32; off >= 1; off >>= 1) {
        a0 += __shfl_xor(a0, off);
        a1 += __shfl_xor(a1, off);
        a2 += __shfl_xor(a2, off);
    }
    __shared__ float red[4][3];
    int wv = t >> 6, ln = t & 63;
    if (ln == 0) { red[wv][0] = a0; red[wv][1] = a1; red[wv][2] = a2; }
    __syncthreads();
    if (t < 3) {
        out[s * 3 + t] = red[0][t] + red[1][t] + red[2][t] + red[3][t] + b[t];
    }
}

// ---------------------------------------------------------------- launch

extern "C" void kernel_launch(void* const* d_in, const int* in_sizes, int n_in,
                              void* d_out, int out_size, void* d_ws, size_t ws_size,
                              hipStream_t stream) {
    const float* x        = (const float*)d_in[0];
    const int*   eidx     = (const int*)  d_in[1];
    const int*   tmask    = (const int*)  d_in[2];
    const float* lin1_W   = (const float*)d_in[3];
    const float* lin1_b   = (const float*)d_in[4];
    const float* convs_W  = (const float*)d_in[5];
    const float* att_dst  = (const float*)d_in[6];
    const float* att_src  = (const float*)d_in[7];
    const float* convs_b  = (const float*)d_in[8];
    const float* lin3_W   = (const float*)d_in[9];
    const float* lin3_b   = (const float*)d_in[10];
    float* out = (float*)d_out;

    char* ws = (char*)d_ws;
    size_t off = 0;
    auto alloc = [&](size_t bytes) -> void* {
        void* p = ws + off;
        off = (off + bytes + 255) & ~(size_t)255;
        return p;
    };
    _Float16* xh   = (_Float16*)alloc((size_t)N_PAD * KP1 * 2);
    _Float16* h    = (_Float16*)alloc((size_t)N_PAD * HID * 2);
    _Float16* hw   = (_Float16*)alloc((size_t)N_NODES * HID * 2);
    _Float16* w1t  = (_Float16*)alloc((size_t)HID * KP1 * 2);
    _Float16* wct  = (_Float16*)alloc((size_t)LAYERS * HID * HID * 2);
    float* sdst    = (float*)alloc((size_t)N_NODES * HEADS * 4);
    float* ssrc    = (float*)alloc((size_t)N_NODES * HEADS * 4);
    int*   counts  = (int*)  alloc((size_t)N_NODES * 4);
    int*   rowptr  = (int*)  alloc((size_t)(N_NODES + 1) * 4);
    int*   cursor  = (int*)  alloc((size_t)N_NODES * 4);
    int*   col     = (int*)  alloc((size_t)EPAD * 4);

    const int* src = eidx;
    const int* tgt = eidx + E_EDGES;

    // CSR build (padded rows; shared by all 4 layers)
    init_counts_kernel<<<(N_NODES + 255) / 256, 256, 0, stream>>>(counts);
    count_edges_kernel<<<(E_EDGES + 255) / 256, 256, 0, stream>>>(tgt, counts);
    scan_kernel<<<1, 256, 0, stream>>>(counts, rowptr, cursor);
    fill_edges_kernel<<<(ETOT + 255) / 256, 256, 0, stream>>>(src, tgt, cursor, col);
    pad_edges_kernel<<<(N_NODES + 255) / 256, 256, 0, stream>>>(cursor, rowptr, col);

    // casts
    cast_x_kernel<<<((long)N_NODES * KP1 + 255) / 256, 256, 0, stream>>>(x, xh);
    cast_w1_kernel<<<(HID * KP1 + 255) / 256, 256, 0, stream>>>(lin1_W, w1t);
    cast_wc_kernel<<<(LAYERS * HID * HID + 255) / 256, 256, 0, stream>>>(convs_W, wct);

    // lin1
    gemm_mfma_kernel<<<dim3((N_NODES + 127) / 128, HID / 128), 256, 0, stream>>>(
        xh, w1t, lin1_b, h, N_NODES, KP1, 1);

    for (int l = 0; l < LAYERS; l++) {
        gemm_mfma_kernel<<<dim3((N_NODES + 127) / 128, HID / 128), 256, 0, stream>>>(
            h, wct + (size_t)l * HID * HID, nullptr, hw, N_NODES, HID, 0);
        score_kernel<<<N_NODES, 256, 0, stream>>>(
            hw, att_dst + (size_t)l * HEADS * OC, att_src + (size_t)l * HEADS * OC, sdst, ssrc);
        agg_kernel<<<(N_NODES + 3) / 4, 256, 0, stream>>>(
            rowptr, counts, col, sdst, ssrc, hw, convs_b + (size_t)l * HID, h);
    }

    head_kernel<<<BSAMP, 256, 0, stream>>>(h, tmask, lin3_W, lin3_b, out);
}

// Round 4
// 1116.187 us; speedup vs baseline: 1.8318x; 1.0513x over previous
//
#include <hip/hip_runtime.h>
#include <math.h>

#define N_NODES 50000
#define N_PAD   50048            // padded rows for 128-row GEMM tiles
#define E_EDGES 1600000
#define ETOT    (E_EDGES + N_NODES)
#define EPAD    (E_EDGES + 8 * N_NODES)   // CSR rows padded to multiple of 8
#define IN_DIM  300
#define KP1     320              // IN_DIM padded to mult of 32
#define HID     256
#define HEADS   8
#define OC      32
#define LAYERS  4
#define BSAMP   1024
#define NEG_SLOPE 0.2f
#define DEG_CAP 128              // fast-path max padded degree per node

// XCD-bucketed CSR build: bucket = blockIdx % 8 pins a node-range's
// cursor/col lines to (heuristically) one XCD's L2.
#define NB  8                    // buckets = XCDs
#define NPB 6250                 // nodes per bucket (50000/8)
#define BPB 256                  // blocks per bucket

typedef _Float16 half8 __attribute__((ext_vector_type(8)));
typedef _Float16 half4v __attribute__((ext_vector_type(4)));
typedef float f32x4 __attribute__((ext_vector_type(4)));

// ---------------------------------------------------------------- CSR build

__global__ __launch_bounds__(256) void init_counts_kernel(int* counts) {
    int i = blockIdx.x * 256 + threadIdx.x;
    if (i < N_NODES) counts[i] = 1;   // self loop pre-counted
}

// bucketed: each bucket's blocks scan all edges, keep only their node range
__global__ __launch_bounds__(256) void count_edges_kernel(const int* __restrict__ tgt, int* counts) {
    int b = blockIdx.x & (NB - 1);
    int i = blockIdx.x / NB;
    int lo = b * NPB, hi = lo + NPB;
    const int chunk = (E_EDGES + BPB - 1) / BPB;
    int beg = i * chunk;
    int end = min(beg + chunk, E_EDGES);
    for (int e = beg + threadIdx.x; e < end; e += 256) {
        int t = tgt[e];
        if (t >= lo && t < hi) atomicAdd(&counts[t], 1);
    }
}

// exclusive scan of PADDED counts -> row_ptr (padded starts), cursor copy
__global__ __launch_bounds__(256) void scan_kernel(const int* __restrict__ counts,
                                                   int* __restrict__ row_ptr,
                                                   int* __restrict__ cursor) {
    __shared__ int sums[256];
    const int CHUNK = (N_NODES + 255) / 256;
    int t = threadIdx.x;
    int beg = t * CHUNK;
    int fin = min(beg + CHUNK, N_NODES);
    int s = 0;
    for (int i = beg; i < fin; i++) s += (counts[i] + 7) & ~7;
    sums[t] = s;
    __syncthreads();
    for (int off = 1; off < 256; off <<= 1) {
        int a = sums[t];
        int u = (t >= off) ? sums[t - off] : 0;
        __syncthreads();
        sums[t] = a + u;
        __syncthreads();
    }
    int running = sums[t] - s;
    for (int i = beg; i < fin; i++) {
        row_ptr[i] = running;
        cursor[i]  = running;
        running += (counts[i] + 7) & ~7;
    }
    if (t == 255) row_ptr[N_NODES] = sums[255];
}

// bucketed scatter: atomic cursor + col writes stay in one bucket's slice
__global__ __launch_bounds__(256) void fill_edges_kernel(const int* __restrict__ src,
                                                         const int* __restrict__ tgt,
                                                         int* cursor, int* __restrict__ col) {
    int b = blockIdx.x & (NB - 1);
    int i = blockIdx.x / NB;
    int lo = b * NPB, hi = lo + NPB;
    const int chunk = (ETOT + BPB - 1) / BPB;
    int beg = i * chunk;
    int end = min(beg + chunk, ETOT);
    for (int e = beg + threadIdx.x; e < end; e += 256) {
        int s_, t_;
        if (e < E_EDGES) { s_ = src[e]; t_ = tgt[e]; }
        else             { s_ = t_ = e - E_EDGES; }
        if (t_ >= lo && t_ < hi) {
            int pos = atomicAdd(&cursor[t_], 1);
            col[pos] = s_;
        }
    }
}

// fill pad slots with the row's own node id (valid index; masked out later)
__global__ __launch_bounds__(256) void pad_edges_kernel(const int* __restrict__ cursor,
                                                        const int* __restrict__ row_ptr,
                                                        int* __restrict__ col) {
    int i = blockIdx.x * 256 + threadIdx.x;
    if (i >= N_NODES) return;
    int e = cursor[i];            // true end after fill
    int pe = row_ptr[i + 1];      // padded end
    for (; e < pe; e++) col[e] = i;
}

// ---------------------------------------------------------------- fp32 -> fp16 casts

__global__ __launch_bounds__(256) void cast_x_kernel(const float* __restrict__ x, _Float16* __restrict__ xh) {
    long i = (long)blockIdx.x * 256 + threadIdx.x;
    if (i >= (long)N_NODES * KP1) return;
    int r = (int)(i / KP1), c = (int)(i % KP1);
    float v = (c < IN_DIM) ? x[(size_t)r * IN_DIM + c] : 0.f;
    xh[i] = (_Float16)v;
}

__global__ __launch_bounds__(256) void cast_w1_kernel(const float* __restrict__ W, _Float16* __restrict__ Wt) {
    int i = blockIdx.x * 256 + threadIdx.x;
    if (i >= HID * KP1) return;
    int n = i / KP1, k = i % KP1;
    float v = (k < IN_DIM) ? W[(size_t)k * HID + n] : 0.f;
    Wt[i] = (_Float16)v;
}

__global__ __launch_bounds__(256) void cast_wc_kernel(const float* __restrict__ W, _Float16* __restrict__ Wt) {
    int i = blockIdx.x * 256 + threadIdx.x;
    if (i >= LAYERS * HID * HID) return;
    int l = i / (HID * HID);
    int r = i % (HID * HID);
    int n = r / HID, k = r % HID;
    Wt[i] = (_Float16)W[(size_t)l * HID * HID + (size_t)k * HID + n];
}

// ---------------------------------------------------------------- fp16 MFMA GEMM
__global__ __launch_bounds__(256) void gemm_mfma_kernel(const _Float16* __restrict__ A,
                                                        const _Float16* __restrict__ Wt,
                                                        const float* __restrict__ bias,
                                                        _Float16* __restrict__ C,
                                                        int M, int Kp, int addbias) {
    __shared__ _Float16 As[128][32];
    __shared__ _Float16 Bs[128][32];
    const int tid = threadIdx.x;
    const int m0 = blockIdx.x * 128;
    const int n0 = blockIdx.y * 128;
    const int w = tid >> 6, lane = tid & 63;
    const int wm = (w & 1) * 64, wn = (w >> 1) * 64;
    const int quad = lane >> 4, m16 = lane & 15;

    f32x4 acc[4][4];
    #pragma unroll
    for (int i = 0; i < 4; i++)
        #pragma unroll
        for (int j = 0; j < 4; j++)
            acc[i][j] = (f32x4){0.f, 0.f, 0.f, 0.f};

    for (int k0 = 0; k0 < Kp; k0 += 32) {
        #pragma unroll
        for (int i = 0; i < 2; i++) {
            int seg = tid + i * 256;
            int row = seg >> 2, off = seg & 3;
            uint4 v = *(const uint4*)&A[(size_t)(m0 + row) * Kp + k0 + off * 8];
            *(uint4*)&As[row][off * 8] = v;
            uint4 u = *(const uint4*)&Wt[(size_t)(n0 + row) * Kp + k0 + off * 8];
            *(uint4*)&Bs[row][off * 8] = u;
        }
        __syncthreads();

        half8 af[4], bf[4];
        #pragma unroll
        for (int i = 0; i < 4; i++) {
            af[i] = *(const half8*)&As[wm + i * 16 + m16][quad * 8];
            bf[i] = *(const half8*)&Bs[wn + i * 16 + m16][quad * 8];
        }
        #pragma unroll
        for (int mi = 0; mi < 4; mi++)
            #pragma unroll
            for (int ni = 0; ni < 4; ni++)
                acc[mi][ni] = __builtin_amdgcn_mfma_f32_16x16x32_f16(af[mi], bf[ni], acc[mi][ni], 0, 0, 0);
        __syncthreads();
    }

    #pragma unroll
    for (int mi = 0; mi < 4; mi++) {
        #pragma unroll
        for (int r = 0; r < 4; r++) {
            int row = m0 + wm + mi * 16 + quad * 4 + r;
            if (row < M) {
                #pragma unroll
                for (int ni = 0; ni < 4; ni++) {
                    int colg = n0 + wn + ni * 16 + m16;
                    float v = acc[mi][ni][r];
                    if (addbias) v += bias[colg];
                    C[(size_t)row * HID + colg] = (_Float16)v;
                }
            }
        }
    }
}

// ---------------------------------------------------------------- attention scores
__global__ __launch_bounds__(256) void score_kernel(const _Float16* __restrict__ hw,
                                                    const float* __restrict__ att_dst,
                                                    const float* __restrict__ att_src,
                                                    float* __restrict__ s_dst,
                                                    float* __restrict__ s_src) {
    int n = blockIdx.x;
    int c = threadIdx.x;
    float v  = (float)hw[(size_t)n * HID + c];
    float vd = v * att_dst[c];
    float vs = v * att_src[c];
    #pragma unroll
    for (int off = 16; off >= 1; off >>= 1) {
        vd += __shfl_xor(vd, off);
        vs += __shfl_xor(vs, off);
    }
    if ((c & 31) == 0) {
        int h = c >> 5;
        s_dst[(size_t)n * HEADS + h] = vd;
        s_src[(size_t)n * HEADS + h] = vs;
    }
}

// ---------------------------------------------------------------- aggregation
__global__ __launch_bounds__(256) void agg_kernel(const int* __restrict__ row_ptr,
                                                  const int* __restrict__ deg_arr,
                                                  const int* __restrict__ col,
                                                  const float* __restrict__ s_dst,
                                                  const float* __restrict__ s_src,
                                                  const _Float16* __restrict__ hw,
                                                  const float* __restrict__ bias,
                                                  _Float16* __restrict__ h_out) {
    __shared__ float aL[4][DEG_CAP * 8];
    __shared__ int  snL[4][DEG_CAP];

    int wv   = threadIdx.x >> 6;
    int lane = threadIdx.x & 63;
    int t = blockIdx.x * 4 + wv;
    if (t >= N_NODES) return;

    int start = row_ptr[t];
    int pdeg  = row_ptr[t + 1] - start;
    int deg   = deg_arr[t];

    int eh  = lane & 7;        // head (phase A)
    int ech = lane >> 3;       // edge slot within group (phase A)
    float sd = s_dst[(size_t)t * HEADS + eh];

    if (pdeg <= DEG_CAP) {
        // ---------- fast path ----------
        float mx = -1e30f;
        int ngrp = pdeg >> 3;
        for (int g = 0; g < ngrp; g++) {
            int slot = g * 8 + ech;
            int sn = col[start + slot];
            float a = sd + s_src[(size_t)sn * HEADS + eh];
            a = (a > 0.f) ? a : NEG_SLOPE * a;
            aL[wv][slot * 8 + eh] = a;
            if (eh == 0) snL[wv][slot] = sn;
            if (slot < deg) mx = fmaxf(mx, a);
        }
        mx = fmaxf(mx, __shfl_xor(mx, 8));
        mx = fmaxf(mx, __shfl_xor(mx, 16));
        mx = fmaxf(mx, __shfl_xor(mx, 32));

        int p  = lane >> 5;          // edge parity
        int c  = lane & 31;          // channel group (8 channels)
        int hh = c >> 2;             // head of my channels
        float mxc = __shfl(mx, hh);

        const half8* hw8 = (const half8*)hw;
        float acc[8] = {0.f, 0.f, 0.f, 0.f, 0.f, 0.f, 0.f, 0.f};
        float dsum = 0.f;

        for (int g = 0; g < ngrp; g++) {
            int base = g * 8;
            int   sns[4];
            half8 v[4];
            float ex[4];
            #pragma unroll
            for (int j = 0; j < 4; j++) sns[j] = snL[wv][base + 2 * j + p];
            #pragma unroll
            for (int j = 0; j < 4; j++) v[j] = hw8[(size_t)sns[j] * 32 + c];
            #pragma unroll
            for (int j = 0; j < 4; j++) {
                int slot = base + 2 * j + p;
                float a = aL[wv][slot * 8 + hh];
                ex[j] = (slot < deg) ? __expf(a - mxc) : 0.f;
                dsum += ex[j];
            }
            #pragma unroll
            for (int j = 0; j < 4; j++)
                #pragma unroll
                for (int i = 0; i < 8; i++)
                    acc[i] += ex[j] * (float)v[j][i];
        }

        dsum += __shfl_xor(dsum, 32);
        #pragma unroll
        for (int i = 0; i < 8; i++) acc[i] += __shfl_xor(acc[i], 32);

        float inv = 1.f / (dsum + 1e-16f);
        if (p == 0) {
            half8 ov;
            #pragma unroll
            for (int i = 0; i < 8; i++) {
                float o = acc[i] * inv + bias[c * 8 + i];
                o = (o > 0.f) ? o : (__expf(o) - 1.f);
                ov[i] = (_Float16)o;
            }
            ((half8*)h_out)[(size_t)t * 32 + c] = ov;
        }
    } else {
        // ---------- slow path (pdeg > DEG_CAP; statistically never) ----------
        int end = start + deg;
        float mx = -1e30f;
        for (int base = start; base < end; base += 8) {
            int e = base + ech;
            if (e < end) {
                int sn = col[e];
                float a = sd + s_src[(size_t)sn * HEADS + eh];
                a = (a > 0.f) ? a : NEG_SLOPE * a;
                mx = fmaxf(mx, a);
            }
        }
        mx = fmaxf(mx, __shfl_xor(mx, 8));
        mx = fmaxf(mx, __shfl_xor(mx, 16));
        mx = fmaxf(mx, __shfl_xor(mx, 32));

        float4 acc = {0.f, 0.f, 0.f, 0.f};
        float dsum = 0.f;
        const half4v* hw4 = (const half4v*)hw;
        int chead = lane >> 3;
        for (int base = start; base < end; base += 8) {
            int e = base + ech;
            float exv = 0.f;
            int sn = 0;
            if (e < end) {
                sn = col[e];
                float a = sd + s_src[(size_t)sn * HEADS + eh];
                a = (a > 0.f) ? a : NEG_SLOPE * a;
                exv = __expf(a - mx);
                dsum += exv;
            }
            int cnt = min(8, end - base);
            for (int j = 0; j < cnt; j++) {
                float exj = __shfl(exv, j * 8 + chead);
                int  snj  = __shfl(sn,  j * 8);
                half4v v = hw4[(size_t)snj * 64 + lane];
                acc.x += exj * (float)v[0];
                acc.y += exj * (float)v[1];
                acc.z += exj * (float)v[2];
                acc.w += exj * (float)v[3];
            }
        }
        dsum += __shfl_xor(dsum, 8);
        dsum += __shfl_xor(dsum, 16);
        dsum += __shfl_xor(dsum, 32);
        float den = __shfl(dsum, chead) + 1e-16f;
        float inv = 1.f / den;
        int cb = lane * 4;
        float o[4] = {acc.x * inv + bias[cb + 0], acc.y * inv + bias[cb + 1],
                      acc.z * inv + bias[cb + 2], acc.w * inv + bias[cb + 3]};
        #pragma unroll
        for (int i = 0; i < 4; i++) o[i] = (o[i] > 0.f) ? o[i] : (__expf(o[i]) - 1.f);
        half4v ov;
        ov[0] = (_Float16)o[0]; ov[1] = (_Float16)o[1];
        ov[2] = (_Float16)o[2]; ov[3] = (_Float16)o[3];
        ((half4v*)h_out)[(size_t)t * 64 + lane] = ov;
    }
}

// ---------------------------------------------------------------- head
__global__ __launch_bounds__(256) void head_kernel(const _Float16* __restrict__ h,
                                                   const int* __restrict__ target_mask,
                                                   const float* __restrict__ W,
                                                   const float* __restrict__ b,
                                                   float* __restrict__ out) {
    int s = blockIdx.x;
    int t = threadIdx.x;
    int n0 = target_mask[s * 2 + 0];
    int n1 = target_mask[s * 2 + 1];
    float f0 = (float)h[(size_t)n0 * HID + t];
    float f1 = (float)h[(size_t)n1 * HID + t];
    float a0 = f0 * W[t * 3 + 0] + f1 * W[(t + 256) * 3 + 0];
    float a1 = f0 * W[t * 3 + 1] + f1 * W[(t + 256) * 3 + 1];
    float a2 = f0 * W[t * 3 + 2] + f1 * W[(t + 256) * 3 + 2];
    #pragma unroll
    for (int off = 32; off >= 1; off >>= 1) {
        a0 += __shfl_xor(a0, off);
        a1 += __shfl_xor(a1, off);
        a2 += __shfl_xor(a2, off);
    }
    __shared__ float red[4][3];
    int wv = t >> 6, ln = t & 63;
    if (ln == 0) { red[wv][0] = a0; red[wv][1] = a1; red[wv][2] = a2; }
    __syncthreads();
    if (t < 3) {
        out[s * 3 + t] = red[0][t] + red[1][t] + red[2][t] + red[3][t] + b[t];
    }
}

// ---------------------------------------------------------------- launch

extern "C" void kernel_launch(void* const* d_in, const int* in_sizes, int n_in,
                              void* d_out, int out_size, void* d_ws, size_t ws_size,
                              hipStream_t stream) {
    const float* x        = (const float*)d_in[0];
    const int*   eidx     = (const int*)  d_in[1];
    const int*   tmask    = (const int*)  d_in[2];
    const float* lin1_W   = (const float*)d_in[3];
    const float* lin1_b   = (const float*)d_in[4];
    const float* convs_W  = (const float*)d_in[5];
    const float* att_dst  = (const float*)d_in[6];
    const float* att_src  = (const float*)d_in[7];
    const float* convs_b  = (const float*)d_in[8];
    const float* lin3_W   = (const float*)d_in[9];
    const float* lin3_b   = (const float*)d_in[10];
    float* out = (float*)d_out;

    char* ws = (char*)d_ws;
    size_t off = 0;
    auto alloc = [&](size_t bytes) -> void* {
        void* p = ws + off;
        off = (off + bytes + 255) & ~(size_t)255;
        return p;
    };
    _Float16* xh   = (_Float16*)alloc((size_t)N_PAD * KP1 * 2);
    _Float16* h    = (_Float16*)alloc((size_t)N_PAD * HID * 2);
    _Float16* hw   = (_Float16*)alloc((size_t)N_NODES * HID * 2);
    _Float16* w1t  = (_Float16*)alloc((size_t)HID * KP1 * 2);
    _Float16* wct  = (_Float16*)alloc((size_t)LAYERS * HID * HID * 2);
    float* sdst    = (float*)alloc((size_t)N_NODES * HEADS * 4);
    float* ssrc    = (float*)alloc((size_t)N_NODES * HEADS * 4);
    int*   counts  = (int*)  alloc((size_t)N_NODES * 4);
    int*   rowptr  = (int*)  alloc((size_t)(N_NODES + 1) * 4);
    int*   cursor  = (int*)  alloc((size_t)N_NODES * 4);
    int*   col     = (int*)  alloc((size_t)EPAD * 4);

    const int* src = eidx;
    const int* tgt = eidx + E_EDGES;

    // CSR build (padded rows, XCD-bucketed scatter; shared by all 4 layers)
    init_counts_kernel<<<(N_NODES + 255) / 256, 256, 0, stream>>>(counts);
    count_edges_kernel<<<NB * BPB, 256, 0, stream>>>(tgt, counts);
    scan_kernel<<<1, 256, 0, stream>>>(counts, rowptr, cursor);
    fill_edges_kernel<<<NB * BPB, 256, 0, stream>>>(src, tgt, cursor, col);
    pad_edges_kernel<<<(N_NODES + 255) / 256, 256, 0, stream>>>(cursor, rowptr, col);

    // casts
    cast_x_kernel<<<((long)N_NODES * KP1 + 255) / 256, 256, 0, stream>>>(x, xh);
    cast_w1_kernel<<<(HID * KP1 + 255) / 256, 256, 0, stream>>>(lin1_W, w1t);
    cast_wc_kernel<<<(LAYERS * HID * HID + 255) / 256, 256, 0, stream>>>(convs_W, wct);

    // lin1
    gemm_mfma_kernel<<<dim3((N_NODES + 127) / 128, HID / 128), 256, 0, stream>>>(
        xh, w1t, lin1_b, h, N_NODES, KP1, 1);

    for (int l = 0; l < LAYERS; l++) {
        gemm_mfma_kernel<<<dim3((N_NODES + 127) / 128, HID / 128), 256, 0, stream>>>(
            h, wct + (size_t)l * HID * HID, nullptr, hw, N_NODES, HID, 0);
        score_kernel<<<N_NODES, 256, 0, stream>>>(
            hw, att_dst + (size_t)l * HEADS * OC, att_src + (size_t)l * HEADS * OC, sdst, ssrc);
        agg_kernel<<<(N_NODES + 3) / 4, 256, 0, stream>>>(
            rowptr, counts, col, sdst, ssrc, hw, convs_b + (size_t)l * HID, h);
    }

    head_kernel<<<BSAMP, 256, 0, stream>>>(h, tmask, lin3_W, lin3_b, out);
}